// Round 11
// baseline (625.382 us; speedup 1.0000x reference)
//
#include <hip/hip_runtime.h>
#include <hip/hip_cooperative_groups.h>
#include <cstdint>

namespace cg = cooperative_groups;

#define B_ 16
#define A_ 32768
#define G_ 100
#define NBLK 1024
#define CPB  64     // blocks per image
#define APB  512    // anchors per block
#define KG   2      // anchors per thread

// One cooperative kernel: phase1 = per-anchor argmax (regs) + per-(b,g) argmax
// (block tasks, direct key store); phase2 = scatter forced; phase3 = loss;
// phase4 = finalize. grid.sync() between phases.
__global__ __launch_bounds__(256, 4) void k_all(
    const float* __restrict__ loc_pred,
    const float* __restrict__ anchors,
    const int*   __restrict__ ignore,
    const float* __restrict__ targets,
    unsigned long long* __restrict__ keys,   // [B_*G_]
    int*   __restrict__ forced,              // [B_*A_]
    float* __restrict__ accum,               // [2]
    float* __restrict__ out)
{
    cg::grid_group grid = cg::this_grid();
    const int bid  = blockIdx.x;
    const int tid  = threadIdx.x;
    const int b    = bid / CPB;
    const int base = (bid % CPB) * APB;

    __shared__ float4 sg[G_];
    __shared__ unsigned long long sk[4];
    __shared__ float ssum[4], scnt[4];

    if (tid < G_) {
        float t0 = targets[(b * G_ + tid) * 3 + 0];
        float t1 = targets[(b * G_ + tid) * 3 + 1];
        float lb = targets[(b * G_ + tid) * 3 + 2];
        sg[tid] = make_float4(t0, t1, t1 - t0, lb);
    }
    if (bid == 0 && tid == 0) { accum[0] = 0.f; accum[1] = 0.f; }
    __syncthreads();

    // ---- phase 1a: per-anchor argmax over g (first-valid-g-wins) ----
    float a0[KG], a1[KG], la[KG], bi[KG], bu[KG], bv[KG];
    int   bg[KG];
#pragma unroll
    for (int k = 0; k < KG; ++k) {
        int a = base + tid + k * 256;
        float2 v = ((const float2*)anchors)[b * A_ + a];
        a0[k] = v.x; a1[k] = v.y; la[k] = v.y - v.x;
        bv[k] = -1.f; bi[k] = -1.f; bu[k] = 1.f; bg[k] = -1;
        forced[b * A_ + a] = -1;                 // init own slots pre-sync
    }
    for (int g = 0; g < G_; ++g) {
        float4 t = sg[g];
        if (!(t.w > 0.f)) continue;              // block-uniform branch
#pragma unroll
        for (int k = 0; k < KG; ++k) {
            float inter = fmaxf(fminf(t.y, a1[k]) - fmaxf(t.x, a0[k]), 0.f);
            float u     = (t.z + la[k]) - inter;
            float iou   = inter * __builtin_amdgcn_rcpf(u);
            if (iou > bv[k]) { bv[k] = iou; bi[k] = inter; bu[k] = u; bg[k] = g; }
        }
    }

    // ---- phase 1b: per-(b,g) argmax over anchors; block t = bid, bid+NBLK ----
    for (int it = 0; it < 2; ++it) {
        int  t      = bid + it * NBLK;
        bool active = (t < B_ * G_);
        float t0 = 0.f, t1 = 0.f, lb = 0.f, lg = 0.f;
        if (active) {
            t0 = targets[t * 3 + 0]; t1 = targets[t * 3 + 1];
            lb = targets[t * 3 + 2]; lg = t1 - t0;
        }
        bool valid = active && (lb > 0.f);       // block-uniform
        unsigned long long key = 0;
        if (valid) {
            int   tb    = t / G_;
            float bestV = -1.f; unsigned bestA = 0;
            const float2* ap = (const float2*)anchors + tb * A_;
#pragma unroll 4
            for (int j = 0; j < A_ / 256; ++j) {
                int a = tid + j * 256;
                float2 v = ap[a];
                float lA    = v.y - v.x;
                float inter = fmaxf(fminf(t1, v.y) - fmaxf(t0, v.x), 0.f);
                float u     = (lg + lA) - inter;
                float iou   = inter * __builtin_amdgcn_rcpf(u);
                if (iou > bestV) { bestV = iou; bestA = (unsigned)a; } // min-a wins
            }
            key = ((unsigned long long)__float_as_uint(bestV) << 32)
                | (unsigned long long)(0xFFFFFFFFu - bestA);
#pragma unroll
            for (int off = 32; off > 0; off >>= 1) {
                unsigned long long o = __shfl_xor(key, off, 64);
                if (o > key) key = o;
            }
        }
        if ((tid & 63) == 0) sk[tid >> 6] = valid ? key : 0;
        __syncthreads();
        if (active && tid == 0) {
            unsigned long long k0 = sk[0];
            for (int w = 1; w < 4; ++w) if (sk[w] > k0) k0 = sk[w];
            keys[t] = k0;                        // direct store, no atomics
        }
        __syncthreads();
    }

    grid.sync();

    // ---- phase 2: scatter forced (last-g-wins via atomicMax) ----
    {
        int gidx = bid * 256 + tid;
        if (gidx < B_ * G_) {
            unsigned long long k0 = keys[gidx];
            if (k0 != 0ull) {                    // 0 <=> invalid g
                int tb = gidx / G_, tg = gidx - tb * G_;
                unsigned aidx = 0xFFFFFFFFu - (unsigned)(k0 & 0xFFFFFFFFull);
                atomicMax(&forced[tb * A_ + aidx], tg);
            }
        }
    }

    grid.sync();

    // ---- phase 3: smooth-L1 loss on positives ----
    float mysum = 0.f, mycnt = 0.f;
#pragma unroll
    for (int k = 0; k < KG; ++k) {
        int a = base + tid + k * 256;
        int f = forced[b * A_ + a];
        float ov; int g;
        if (f >= 0) { g = f; ov = 2.f; }
        else        { g = bg[k]; ov = bi[k] / bu[k]; }  // exact IEEE div
        bool pos = false;
        if (g >= 0)
            pos = (ignore[b * A_ + a] == 0) && (ov >= 0.5f) && (sg[g].w > 0.f);
        if (pos) {
            float4 m  = sg[g];
            float ac  = (a0[k] + a1[k]) * 0.5f;
            float asz = la[k];
            float gc  = (m.x + m.y) * 0.5f;
            float gsz = m.y - m.x;
            float lt0 = (gc - ac) / (0.1f * asz);
            float lt1 = logf(gsz / asz) / 0.2f;
            float2 lp = ((const float2*)loc_pred)[b * A_ + a];
            float d0 = lp.x - lt0, d1 = lp.y - lt1;
            float ad0 = fabsf(d0), ad1 = fabsf(d1);
            mysum += (ad0 < 1.f ? 0.5f * d0 * d0 : ad0 - 0.5f)
                   + (ad1 < 1.f ? 0.5f * d1 * d1 : ad1 - 0.5f);
            mycnt += 1.f;
        }
    }
#pragma unroll
    for (int off = 32; off > 0; off >>= 1) {
        mysum += __shfl_down(mysum, off, 64);
        mycnt += __shfl_down(mycnt, off, 64);
    }
    if ((tid & 63) == 0) { ssum[tid >> 6] = mysum; scnt[tid >> 6] = mycnt; }
    __syncthreads();
    if (tid == 0) {
        float s = ssum[0] + ssum[1] + ssum[2] + ssum[3];
        float c = scnt[0] + scnt[1] + scnt[2] + scnt[3];
        if (s != 0.f || c != 0.f) {
            atomicAdd(&accum[0], s);
            atomicAdd(&accum[1], c);
        }
    }

    grid.sync();

    // ---- phase 4: finalize ----
    if (bid == 0 && tid == 0) out[0] = accum[0] / accum[1];
}

// ---------------------------------------------------------------------------
extern "C" void kernel_launch(void* const* d_in, const int* in_sizes, int n_in,
                              void* d_out, int out_size, void* d_ws, size_t ws_size,
                              hipStream_t stream) {
    const float* loc_pred = (const float*)d_in[0];
    // d_in[1] = conf_pred : unused by the loss
    const float* anchors  = (const float*)d_in[2];
    const int*   ignore   = (const int*)d_in[3];
    const float* targets  = (const float*)d_in[4];
    float*       out      = (float*)d_out;

    char* ws = (char*)d_ws;
    unsigned long long* keys = (unsigned long long*)ws;        // 12800 B
    float* accum             = (float*)(ws + 13312);           // 8 B
    int*   forced            = (int*)(ws + 16384);             // 2 MB

    void* args[] = { (void*)&loc_pred, (void*)&anchors, (void*)&ignore,
                     (void*)&targets,  (void*)&keys,    (void*)&forced,
                     (void*)&accum,    (void*)&out };
    hipLaunchCooperativeKernel((void*)k_all, dim3(NBLK), dim3(256),
                               args, 0, stream);
}

// Round 14
// 378.608 us; speedup vs baseline: 1.6518x; 1.6518x over previous
//
#include <hip/hip_runtime.h>
#include <cstdint>

#define B_  16
#define A_  32768
#define G_  100
#define CPB 64      // chunks (blocks) per image
#define APB 512     // anchors per block
#define KG  2       // anchors per thread

// ---------------------------------------------------------------------------
// k_match: per-anchor argmax over g (regs, first-valid-g-wins) fused with
// per-g argmax over anchors (wave butterfly on the SAME iou values + one
// u64 atomicMax per wave per g). Output: bg8[b,a] = matched g if
// overlap>=0.5 (exact via 2*inter>=union), else -1.  keys[b,g] gets the
// packed (iou_bits<<32)|~anchor_idx winner (min-idx tie-break).
// ---------------------------------------------------------------------------
__global__ __launch_bounds__(256) void k_match(
    const float* __restrict__ anchors,       // [B,A,2]
    const float* __restrict__ targets,       // [B,G,3]
    unsigned long long* __restrict__ keys,   // [B*G], zeroed
    signed char* __restrict__ bg8)           // [B*A]
{
    __shared__ float4 sg[G_];
    const int b    = blockIdx.y;
    const int tid  = threadIdx.x;
    const int base = blockIdx.x * APB;

    if (tid < G_) {
        float t0 = targets[(b * G_ + tid) * 3 + 0];
        float t1 = targets[(b * G_ + tid) * 3 + 1];
        float lb = targets[(b * G_ + tid) * 3 + 2];
        sg[tid] = make_float4(t0, t1, t1 - t0, lb);
    }
    __syncthreads();

    float a0[KG], a1[KG], la[KG], bi[KG], bu[KG], bv[KG];
    int   bg[KG];
#pragma unroll
    for (int k = 0; k < KG; ++k) {
        float2 v = ((const float2*)anchors)[b * A_ + base + tid + k * 256];
        a0[k] = v.x; a1[k] = v.y; la[k] = v.y - v.x;
        bi[k] = -1.f; bu[k] = 1.f; bv[k] = -1.f; bg[k] = -1;
    }

    for (int g = 0; g < G_; ++g) {
        float4 t = sg[g];
        if (!(t.w > 0.f)) continue;          // invalid g: uniform skip
        float    gBest = -1.f;
        unsigned gA    = 0;
#pragma unroll
        for (int k = 0; k < KG; ++k) {
            float inter = fmaxf(fminf(t.y, a1[k]) - fmaxf(t.x, a0[k]), 0.f);
            float u     = (t.z + la[k]) - inter;
            float iou   = inter * __builtin_amdgcn_rcpf(u);
            if (iou > bv[k]) { bv[k] = iou; bi[k] = inter; bu[k] = u; bg[k] = g; }
            if (iou > gBest) { gBest = iou; gA = (unsigned)(base + tid + k * 256); }
        }
        // pack: high = iou bits (iou>=0 so monotone), low = ~idx (min-idx wins)
        unsigned long long key =
            ((unsigned long long)__float_as_uint(gBest) << 32) |
            (unsigned long long)(0xFFFFFFFFu - gA);
#pragma unroll
        for (int off = 32; off > 0; off >>= 1) {
            unsigned long long o = __shfl_xor(key, off, 64);
            if (o > key) key = o;
        }
        if ((tid & 63) == 0) atomicMax(&keys[b * G_ + g], key);
    }

#pragma unroll
    for (int k = 0; k < KG; ++k) {
        int a = base + tid + k * 256;
        // overlap >= 0.5  <=>  2*inter >= union  (exact, no division)
        bool ge05 = (bi[k] + bi[k]) >= bu[k];
        bg8[b * A_ + a] = ge05 ? (signed char)bg[k] : (signed char)(-1);
    }
}

// ---------------------------------------------------------------------------
// k_loss: decode keys -> per-block LDS forced table (last-g-wins via LDS
// atomicMax), smooth-L1 over positives, block reduce, ticket finalize.
// ---------------------------------------------------------------------------
__global__ __launch_bounds__(256) void k_loss(
    const float* __restrict__ loc_pred,
    const float* __restrict__ anchors,
    const int*   __restrict__ ignore,
    const float* __restrict__ targets,
    const unsigned long long* __restrict__ keys,
    const signed char* __restrict__ bg8,
    float*    __restrict__ accum,            // [2], zeroed
    unsigned* __restrict__ ticket,           // [1], zeroed
    float*    __restrict__ out)
{
    __shared__ float4 sg[G_];
    __shared__ int    table[APB];
    __shared__ float  ssum[4], scnt[4];
    const int b    = blockIdx.y;
    const int tid  = threadIdx.x;
    const int base = blockIdx.x * APB;

    if (tid < G_) {
        float t0 = targets[(b * G_ + tid) * 3 + 0];
        float t1 = targets[(b * G_ + tid) * 3 + 1];
        sg[tid] = make_float4(t0, t1, 0.f, 0.f);
    }
    table[tid] = -1; table[tid + 256] = -1;
    __syncthreads();
    if (tid < G_) {
        unsigned long long k0 = keys[b * G_ + tid];
        if (k0 != 0ull) {                    // 0 <=> invalid g (never written)
            unsigned aidx = 0xFFFFFFFFu - (unsigned)(k0 & 0xFFFFFFFFull);
            unsigned rel  = aidx - (unsigned)base;
            if (rel < (unsigned)APB) atomicMax(&table[rel], tid);
        }
    }
    __syncthreads();

    float mysum = 0.f, mycnt = 0.f;
#pragma unroll
    for (int k = 0; k < KG; ++k) {
        int a = base + tid + k * 256;
        int i = b * A_ + a;
        int f = table[tid + k * 256];
        int g = (f >= 0) ? f : (int)bg8[i];  // forced overrides, else matched
        bool pos = (g >= 0) && (ignore[i] == 0);
        if (pos) {
            float4 m  = sg[g];
            float2 av = ((const float2*)anchors)[i];
            float ac  = (av.x + av.y) * 0.5f;
            float asz = av.y - av.x;
            float gc  = (m.x + m.y) * 0.5f;
            float gsz = m.y - m.x;
            float lt0 = (gc - ac) / (0.1f * asz);
            float lt1 = logf(gsz / asz) / 0.2f;
            float2 lp = ((const float2*)loc_pred)[i];
            float d0 = lp.x - lt0, d1 = lp.y - lt1;
            float ad0 = fabsf(d0), ad1 = fabsf(d1);
            mysum += (ad0 < 1.f ? 0.5f * d0 * d0 : ad0 - 0.5f)
                   + (ad1 < 1.f ? 0.5f * d1 * d1 : ad1 - 0.5f);
            mycnt += 1.f;
        }
    }
#pragma unroll
    for (int off = 32; off > 0; off >>= 1) {
        mysum += __shfl_down(mysum, off, 64);
        mycnt += __shfl_down(mycnt, off, 64);
    }
    if ((tid & 63) == 0) { ssum[tid >> 6] = mysum; scnt[tid >> 6] = mycnt; }
    __syncthreads();
    if (tid == 0) {
        float s = ssum[0] + ssum[1] + ssum[2] + ssum[3];
        float c = scnt[0] + scnt[1] + scnt[2] + scnt[3];
        if (s != 0.f || c != 0.f) {
            atomicAdd(&accum[0], s);
            atomicAdd(&accum[1], c);
        }
        __threadfence();
        unsigned old = atomicAdd(ticket, 1u);
        if (old == (unsigned)(CPB * B_ - 1)) {      // last block finalizes
            float fs = atomicAdd(&accum[0], 0.f);   // coherent L2 read
            float fc = atomicAdd(&accum[1], 0.f);
            out[0] = fs / fc;
        }
    }
}

// ---------------------------------------------------------------------------
extern "C" void kernel_launch(void* const* d_in, const int* in_sizes, int n_in,
                              void* d_out, int out_size, void* d_ws, size_t ws_size,
                              hipStream_t stream) {
    const float* loc_pred = (const float*)d_in[0];
    // d_in[1] = conf_pred : unused by the loss
    const float* anchors  = (const float*)d_in[2];
    const int*   ignore   = (const int*)d_in[3];
    const float* targets  = (const float*)d_in[4];
    float*       out      = (float*)d_out;

    char* ws = (char*)d_ws;
    unsigned long long* keys = (unsigned long long*)ws;   // 12800 B
    float*       accum  = (float*)(ws + 12800);           // 8 B
    unsigned*    ticket = (unsigned*)(ws + 12808);        // 4 B
    signed char* bg8    = (signed char*)(ws + 13312);     // 512 KB

    hipMemsetAsync(ws, 0, 13312, stream);
    k_match<<<dim3(CPB, B_), 256, 0, stream>>>(anchors, targets, keys, bg8);
    k_loss <<<dim3(CPB, B_), 256, 0, stream>>>(loc_pred, anchors, ignore,
                                               targets, keys, bg8,
                                               accum, ticket, out);
}